// Round 15
// baseline (364.648 us; speedup 1.0000x reference)
//
#include <hip/hip_runtime.h>

// Fused 4-layer MLP (2 -> 1024 -> 512 -> 256 -> 3), N = 262144, fp32 I/O.
// R22 = R21 + CONSTANT REMATERIALIZATION (R18's register-diet trick applied
// to the best kernel). R21 counters don't add up: VALUBusy 24% = 22K cy/SIMD
// vs ~9K of source VALU, and WRITE_SIZE 5120KB vs 3072KB output = 2MB scratch
// — classic allocator copy/spill behavior at VGPR=128-at-cap. zero16 (16
// VGPR) and ones (4 VGPR) were function-lifetime locals LIVE THROUGH the
// peak-pressure ks-loop despite being trivially rematerializable. R22: zf()
// and mk_ones() built at each use site (prologue, 3 regens, tail inits) —
// ~20 arch-VGPR of long-range pressure freed, a few v_movs added at cold
// sites. Everything else byte-identical to R21 (lgkmcnt-only barriers, skew,
// setprio, af 2-deep, bf 1-ahead).
// fp16 MFMA 32x32x16, fp32 accumulate, transposed layers D[feat][batch].

typedef _Float16 f16;
typedef f16 f16x8 __attribute__((ext_vector_type(8)));
typedef f16 f16x4 __attribute__((ext_vector_type(4)));
typedef float f32x16 __attribute__((ext_vector_type(16)));

#define MFMA(a, b, c) __builtin_amdgcn_mfma_f32_32x32x16_f16((a), (b), (c), 0, 0, 0)

// lgkmcnt-only workgroup barrier: LDS writes visible, VMEM loads (register
// prefetches) stay in flight.
#define BARRIER() asm volatile("s_waitcnt lgkmcnt(0)\n\ts_barrier" ::: "memory")

// ws layout in 16-byte units (f16x8):
//  W1F : [16 jt][64 ks][64 lane]            ->      0 .. 65536
//  W2F : [ 8 jt][32 ks][64 lane]            ->  65536 .. 81920
//  W3F : [16 ks][64 lane]                   ->  81920 .. 82944
//  P0F : [32 k1t][64 lane] (layer1 A frag)  ->  82944 .. 84992
//  B1F : [16 jt][64 lane]                   ->  84992 .. 86016
//  B2F : [ 8 jt][64 lane]                   ->  86016 .. 86528
#define U_W1F 0
#define U_W2F 65536
#define U_W3F 81920
#define U_P0F 82944
#define U_B1F 84992
#define U_B2F 86016
#define U_TOTAL 86528

__global__ void prep_kernel(const float* __restrict__ W0, const float* __restrict__ b0,
                            const float* __restrict__ W1, const float* __restrict__ b1,
                            const float* __restrict__ W2, const float* __restrict__ b2,
                            const float* __restrict__ W3, f16* __restrict__ ws)
{
    int u = blockIdx.x * 256 + threadIdx.x;
    if (u >= U_TOTAL) return;
    int lane = u & 63;
    int l31 = lane & 31;
    int q = lane >> 5;
    f16x8 v;
#pragma unroll
    for (int e = 0; e < 8; ++e) v[e] = (f16)0.f;

    if (u < U_W2F) {                       // W1F: W1 is [1024][512]
        int jt = u >> 12, ks = (u >> 6) & 63;
        int j = jt * 32 + l31;
        int kb = ks * 16 + q * 8;
        const float* p = W1 + (size_t)kb * 512 + j;
#pragma unroll
        for (int e = 0; e < 8; ++e) v[e] = (f16)p[(size_t)e * 512];
    } else if (u < U_W3F) {                // W2F: W2 is [512][256]
        int t = u - U_W2F;
        int jt = t >> 11, ks = (t >> 6) & 31;
        int j = jt * 32 + l31;
        int kb = ks * 16 + q * 8;
        const float* p = W2 + (size_t)kb * 256 + j;
#pragma unroll
        for (int e = 0; e < 8; ++e) v[e] = (f16)p[(size_t)e * 256];
    } else if (u < U_P0F) {                // W3F: W3 is [256][3], pad j>=3 with 0
        int t = u - U_W3F;
        int ks = t >> 6;
        int j = l31;
        int kb = ks * 16 + q * 8;
        if (j < 3) {
            const float* p = W3 + (size_t)kb * 3 + j;
#pragma unroll
            for (int e = 0; e < 8; ++e) v[e] = (f16)p[(size_t)e * 3];
        }
    } else if (u < U_B1F) {                // P0F: layer-1 A frag with hi/lo split + bias
        int t = u - U_P0F;
        int jt = t >> 6;
        int j = jt * 32 + l31;
        if (q == 0) {
            float w00 = W0[j], w01 = W0[1024 + j], bb = b0[j];
            f16 w00h = (f16)w00, w01h = (f16)w01, bh = (f16)bb;
            v[0] = w00h; v[1] = w01h; v[2] = bh;
            v[3] = w00h; v[4] = w01h;                       // pair with x_lo
            v[5] = (f16)(w00 - (float)w00h);                // w_lo * x_hi
            v[6] = (f16)(w01 - (float)w01h);
            v[7] = (f16)(bb - (float)bh);                   // bias residual * 1
        }
    } else if (u < U_B2F) {                // B1F
        int t = u - U_B1F;
        int jt = t >> 6;
        int j = jt * 32 + l31;
        if (q == 0) v[0] = (f16)b1[j];
    } else {                               // B2F
        int t = u - U_B2F;
        int jt = t >> 6;
        int j = jt * 32 + l31;
        if (q == 0) v[0] = (f16)b2[j];
    }
    ((f16x8*)ws)[u] = v;
}

// ---- LDS slab, 16B-chunk XOR swizzle.
// Logical: row m (batch), 16B chunk c (8 f16 feats). Physical chunk =
// c ^ (m & 15). Bijective; spreads the bank-aligned row stride.
__device__ __forceinline__ void slab_wr8(unsigned char* lds_, int m, int c, int q8,
                                         int rs, f16x4 val)
{
    *(f16x4*)(lds_ + (size_t)m * rs + (size_t)(((c ^ (m & 15)) << 4) + q8)) = val;
}

__device__ __forceinline__ f16x8 slab_rd(const unsigned char* p, int rowbyte, int physc)
{
    return *(const f16x8*)(p + (size_t)rowbyte + (size_t)(physc << 4));
}

__device__ __forceinline__ f16x4 relu_pack4(const f32x16& d, int t)
{
    f16x4 pk;
#pragma unroll
    for (int r = 0; r < 4; ++r) {
        float v = d[4 * t + r];
        pk[r] = (f16)(v > 0.f ? v : 0.f);
    }
    return pk;
}

// rematerializable constants: built at each use site so nothing is live
// across the peak-pressure ks-loop (R18 lesson; zero16 was 16 VGPR for the
// whole function, ones was 4).
__device__ __forceinline__ f32x16 zf()
{
    f32x16 z;
#pragma unroll
    for (int i = 0; i < 16; ++i) z[i] = 0.f;
    return z;
}

__device__ __forceinline__ f16x8 mk_ones(int q)
{
    f16x8 o;
#pragma unroll
    for (int e = 0; e < 8; ++e) o[e] = (f16)0.f;
    if (q == 0) o[0] = (f16)1.f;
    return o;
}

__global__ __launch_bounds__(512, 2)
void mlp_kernel(const float* __restrict__ X, const float* __restrict__ b3,
                const f16* __restrict__ ws, float* __restrict__ out)
{
    const f16x8* W1F = (const f16x8*)ws + U_W1F;
    const f16x8* W2F = (const f16x8*)ws + U_W2F;
    const f16x8* W3F = (const f16x8*)ws + U_W3F;
    const f16x8* P0F = (const f16x8*)ws + U_P0F;
    const f16x8* B1F = (const f16x8*)ws + U_B1F;
    const f16x8* B2F = (const f16x8*)ws + U_B2F;

    // 2 x 64KB dbuf chunk slabs (128 rows x 256 f16, rs=512B);
    // tail: whole 128KB = h2 slab (rs=1024B), then lower 64KB = h3 slab.
    __shared__ __align__(16) unsigned char lds[131072];

    const int tid  = threadIdx.x;
    const int w    = tid >> 6;       // wave 0..7
    const int lane = tid & 63;
    const int l31  = lane & 31;
    const int q    = lane >> 5;
    const int q8   = q << 3;
    const int pre  = q ^ (l31 & 15); // physc = (2ks) ^ pre
    const int ph   = w >> 2;         // ks-rotation phase: co-SIMD pair (w, w+4)
    const int preR = pre ^ (ph << 4);          // rotation folded into bf swizzle
    const int inc7  = ph ? -960 : 64;          // af walk: jump at loaded-pos 7->8
    const int inc15 = ph ? 1088 : 64;          // af walk: chunk boundary jump
    const size_t rowbase = (size_t)blockIdx.x * 128;

    // X frags, all 4 m-tiles (hi/lo split -> layer 1 ~exact); 16 regs
    f16x8 xfrag[4];
#pragma unroll
    for (int mt = 0; mt < 4; ++mt) {
        f16x8 v;
#pragma unroll
        for (int e = 0; e < 8; ++e) v[e] = (f16)0.f;
        if (q == 0) {
            float2 xv = ((const float2*)X)[rowbase + mt * 32 + l31];
            f16 x0h = (f16)xv.x, x1h = (f16)xv.y;
            v[0] = x0h; v[1] = x1h; v[2] = (f16)1.f;
            v[3] = (f16)(xv.x - (float)x0h);
            v[4] = (f16)(xv.y - (float)x1h);
            v[5] = x0h; v[6] = x1h; v[7] = (f16)1.f;
        }
        xfrag[mt] = v;
    }

    // Layer-2 ownership: wave w -> jt {2w, 2w+1} x all 4 mt. acc = 128 AGPR.
    f32x16 acc2[2][4];
#pragma unroll
    for (int ji = 0; ji < 2; ++ji) {
        f32x16 binit = MFMA(B1F[(2 * w + ji) * 64 + lane], mk_ones(q), zf());
#pragma unroll
        for (int mt = 0; mt < 4; ++mt) acc2[ji][mt] = binit;
    }

    // af streams: W1F jt-slices {2w, 2w+1}, 2-deep staging, rotated order.
    // af(s) = s*64 + (ph ? (s%16<8 ? +512 : -512) : 0); walk via inc7/inc15.
    const f16x8* __restrict__ ap0 = W1F + (size_t)(2 * w * 64) * 64 + lane + (ph << 9);
    const f16x8* __restrict__ ap1 = ap0 + 64 * 64;
    f16x8 a0c = ap0[0],  a1c = ap1[0];     // af[s=0]
    f16x8 a0n = ap0[64], a1n = ap1[64];    // af[s=1]
    ap0 += 128; ap1 += 128;                // next load = af[s=2]

    // prologue: layer1 chunk 0 -> buf0. Wave w: k1-tile w, all 4 m-tiles.
    {
        f16x8 af1 = P0F[w * 64 + lane];
#pragma unroll
        for (int mt = 0; mt < 4; ++mt) {
            f32x16 d = MFMA(af1, xfrag[mt], zf());
            int m = mt * 32 + l31;
#pragma unroll
            for (int t = 0; t < 4; ++t)
                slab_wr8(lds, m, w * 4 + t, q8, 512, relu_pack4(d, t));
        }
    }
    BARRIER();

    const int r0 = l31 * 512;              // bf row-byte bases, chunk slab
    const int r1 = r0 + 32 * 512;
    const int r2 = r0 + 64 * 512;
    const int r3 = r0 + 96 * 512;

    // ---- fused layer1+layer2: K chunked 4 x 256, dbuf slabs, 1 barrier/chunk.
    // Each wave consumes the chunk's 16 ks rotated by 8*ph (order-invariant).
    for (int c = 0; c < 4; ++c) {
        const unsigned char* rb = lds + (size_t)(c & 1) * 65536;
        // P0F for the NEXT chunk's regen: issue ~8K cy ahead of use.
        f16x8 p0nx;
        if (c < 3) p0nx = P0F[((c + 1) * 8 + w) * 64 + lane];
        // cold-start bf[kk=0] for this chunk (rotated slot = preR fold)
        f16x8 b0 = slab_rd(rb, r0, preR);
        f16x8 b1 = slab_rd(rb, r1, preR);
        f16x8 b2 = slab_rd(rb, r2, preR);
        f16x8 b3f = slab_rd(rb, r3, preR);
#pragma unroll
        for (int ks = 0; ks < 16; ++ks) {
            // issue af[s+2] (2-deep slack ~2 ks-rounds >> L2 latency)
            f16x8 a0f = ap0[0], a1f = ap1[0];
            int inc = (ks == 5) ? inc7 : (ks == 13) ? inc15 : 64;
            ap0 += inc; ap1 += inc;        // final overrun into W2F: in-bounds
            // issue bf[kk+1] (1-ahead slack ~1 ks-round >> LDS latency)
            f16x8 n0, n1, n2, n3;
            if (ks < 15) {
                int pc = (2 * (ks + 1)) ^ preR;
                n0 = slab_rd(rb, r0, pc);
                n1 = slab_rd(rb, r1, pc);
                n2 = slab_rd(rb, r2, pc);
                n3 = slab_rd(rb, r3, pc);
            }
            // 8 MFMAs on staged operands (T5: prio boost the MFMA cluster)
            __builtin_amdgcn_s_setprio(1);
            acc2[0][0] = MFMA(a0c, b0,  acc2[0][0]);
            acc2[0][1] = MFMA(a0c, b1,  acc2[0][1]);
            acc2[1][0] = MFMA(a1c, b0,  acc2[1][0]);
            acc2[1][1] = MFMA(a1c, b1,  acc2[1][1]);
            acc2[0][2] = MFMA(a0c, b2,  acc2[0][2]);
            acc2[0][3] = MFMA(a0c, b3f, acc2[0][3]);
            acc2[1][2] = MFMA(a1c, b2,  acc2[1][2]);
            acc2[1][3] = MFMA(a1c, b3f, acc2[1][3]);
            __builtin_amdgcn_s_setprio(0);
            // rotate stages (full unroll -> pure SSA renames)
            a0c = a0n; a1c = a1n; a0n = a0f; a1n = a1f;
            if (ks < 15) { b0 = n0; b1 = n1; b2 = n2; b3f = n3; }
        }
        // layer 1 for next chunk -> other buffer (P0F already in p0nx)
        if (c < 3) {
            unsigned char* wb = lds + (size_t)((c + 1) & 1) * 65536;
#pragma unroll
            for (int mt = 0; mt < 4; ++mt) {
                f32x16 d = MFMA(p0nx, xfrag[mt], zf());
                int m = mt * 32 + l31;
#pragma unroll
                for (int tt = 0; tt < 4; ++tt)
                    slab_wr8(wb, m, w * 4 + tt, q8, 512, relu_pack4(d, tt));
            }
        }
        BARRIER();
    }

    // ---- tail: stage h2 (128 rows x 512 f16, rs=1024B = 128KB).
#pragma unroll
    for (int ji = 0; ji < 2; ++ji) {
#pragma unroll
        for (int mt = 0; mt < 4; ++mt) {
            int m = mt * 32 + l31;
#pragma unroll
            for (int t = 0; t < 4; ++t)
                slab_wr8(lds, m, (2 * w + ji) * 4 + t, q8, 1024,
                         relu_pack4(acc2[ji][mt], t));
        }
    }
    BARRIER();

    // layer 3: wave (jp3 = w&3, mq = w>>2) -> jt {2jp3, 2jp3+1} x mt {2mq, 2mq+1};
    // K=512. Pipelined: af 2-deep, bf 1-ahead. acc3 = 64 AGPR.
    // Co-SIMD diversity here comes from mq differing for (w, w+4).
    const int jp3 = w & 3;
    const int mq  = w >> 2;
    f32x16 acc3[2][2];
#pragma unroll
    for (int ji = 0; ji < 2; ++ji) {
        f32x16 binit = MFMA(B2F[(2 * jp3 + ji) * 64 + lane], mk_ones(q), zf());
        acc3[ji][0] = binit;
        acc3[ji][1] = binit;
    }
    {
        const f16x8* __restrict__ bp0 = W2F + (size_t)(2 * jp3 * 32) * 64 + lane;
        const f16x8* __restrict__ bp1 = bp0 + 32 * 64;
        f16x8 c0c = bp0[0],  c1c = bp1[0];
        f16x8 c0n = bp0[64], c1n = bp1[64];
        bp0 += 128; bp1 += 128;
        const int s0 = (mq * 64 + l31) * 1024;   // h2 slab rows, rs=1024
        const int s1 = s0 + 32 * 1024;
        f16x8 d0 = slab_rd(lds, s0, pre);
        f16x8 d1 = slab_rd(lds, s1, pre);
#pragma unroll
        for (int ks = 0; ks < 32; ++ks) {
            f16x8 c0f = bp0[0], c1f = bp1[0];
            bp0 += 64; bp1 += 64;          // final overrun into W3F: in-bounds
            f16x8 e0, e1;
            if (ks < 31) {
                int pc = (2 * (ks + 1)) ^ pre;
                e0 = slab_rd(lds, s0, pc);
                e1 = slab_rd(lds, s1, pc);
            }
            __builtin_amdgcn_s_setprio(1);
            acc3[0][0] = MFMA(c0c, d0, acc3[0][0]);
            acc3[0][1] = MFMA(c0c, d1, acc3[0][1]);
            acc3[1][0] = MFMA(c1c, d0, acc3[1][0]);
            acc3[1][1] = MFMA(c1c, d1, acc3[1][1]);
            __builtin_amdgcn_s_setprio(0);
            c0c = c0n; c1c = c1n; c0n = c0f; c1n = c1f;
            if (ks < 31) { d0 = e0; d1 = e1; }
        }
    }
    BARRIER();

    // stage h3 (128 rows x 256 f16, rs=512B = 64KB, lower half of slab)
    {
#pragma unroll
        for (int ji = 0; ji < 2; ++ji) {
#pragma unroll
            for (int mi = 0; mi < 2; ++mi) {
                int m = mq * 64 + mi * 32 + l31;
#pragma unroll
                for (int t = 0; t < 4; ++t)
                    slab_wr8(lds, m, (2 * jp3 + ji) * 4 + t, q8, 512,
                             relu_pack4(acc3[ji][mi], t));
            }
        }
    }
    BARRIER();

    // layer 4: waves 0..3 -> the four 32-row tiles (j padded, 3 valid).
    if (w < 4) {
        f32x16 acc4 = zf();
        const int s4 = (w * 32 + l31) * 512;
#pragma unroll
        for (int ks = 0; ks < 16; ++ks) {
            f16x8 af = W3F[ks * 64 + lane];
            f16x8 bf = slab_rd(lds, s4, (2 * ks) ^ pre);
            acc4 = MFMA(af, bf, acc4);
        }
        if (q == 0) {
            size_t gm = rowbase + w * 32 + l31;
            out[gm * 3 + 0] = acc4[0] + b3[0];
            out[gm * 3 + 1] = acc4[1] + b3[1];
            out[gm * 3 + 2] = acc4[2] + b3[2];
        }
    }
}

extern "C" void kernel_launch(void* const* d_in, const int* in_sizes, int n_in,
                              void* d_out, int out_size, void* d_ws, size_t ws_size,
                              hipStream_t stream)
{
    const float* X  = (const float*)d_in[0];
    const float* W0 = (const float*)d_in[1];
    const float* b0 = (const float*)d_in[2];
    const float* W1 = (const float*)d_in[3];
    const float* b1 = (const float*)d_in[4];
    const float* W2 = (const float*)d_in[5];
    const float* b2 = (const float*)d_in[6];
    const float* W3 = (const float*)d_in[7];
    const float* b3 = (const float*)d_in[8];
    f16* ws = (f16*)d_ws;

    int N = in_sizes[0] / 2;          // 262144
    int nblk = N / 128;               // 2048

    prep_kernel<<<(U_TOTAL + 255) / 256, 256, 0, stream>>>(W0, b0, W1, b1, W2, b2, W3, ws);
    mlp_kernel<<<nblk, 512, 0, stream>>>(X, b3, ws, (float*)d_out);
}

// Round 16
// 362.297 us; speedup vs baseline: 1.0065x; 1.0065x over previous
//
#include <hip/hip_runtime.h>

// Fused 4-layer MLP (2 -> 1024 -> 512 -> 256 -> 3), N = 262144, fp32 I/O.
// R23 = R22 + UNCONDITIONAL (WRAPPED) PREFETCH ROTATIONS. R22's remat was
// null -> constants weren't the phantom-VALU source. Remaining source-level
// copy generator: the conditional rotations "if(ks<15){b0=n0;...}" create
// conditionally-defined values merged into loop-carried registers; after
// full unroll the allocator resolves these phi-merges with v_mov chains
// (~4x4 regs x 64 iters ~ 8K cy/SIMD — matches the unexplained VALU).
// Fix: wrap the prefetch slot ((ks+1)&15 main, (ks+1)&31 L3) so the last
// iteration's prefetch is in-bounds (<=512/<=1024B within row) and the
// rotation becomes unconditional pure SSA. Dead last loads: 4 LDS reads per
// chunk. Everything else identical to R22 (lgkmcnt-only barriers, skew,
// setprio, af 2-deep, bf 1-ahead, remat'd constants).
// fp16 MFMA 32x32x16, fp32 accumulate, transposed layers D[feat][batch].

typedef _Float16 f16;
typedef f16 f16x8 __attribute__((ext_vector_type(8)));
typedef f16 f16x4 __attribute__((ext_vector_type(4)));
typedef float f32x16 __attribute__((ext_vector_type(16)));

#define MFMA(a, b, c) __builtin_amdgcn_mfma_f32_32x32x16_f16((a), (b), (c), 0, 0, 0)

// lgkmcnt-only workgroup barrier: LDS writes visible, VMEM loads (register
// prefetches) stay in flight.
#define BARRIER() asm volatile("s_waitcnt lgkmcnt(0)\n\ts_barrier" ::: "memory")

// ws layout in 16-byte units (f16x8):
//  W1F : [16 jt][64 ks][64 lane]            ->      0 .. 65536
//  W2F : [ 8 jt][32 ks][64 lane]            ->  65536 .. 81920
//  W3F : [16 ks][64 lane]                   ->  81920 .. 82944
//  P0F : [32 k1t][64 lane] (layer1 A frag)  ->  82944 .. 84992
//  B1F : [16 jt][64 lane]                   ->  84992 .. 86016
//  B2F : [ 8 jt][64 lane]                   ->  86016 .. 86528
#define U_W1F 0
#define U_W2F 65536
#define U_W3F 81920
#define U_P0F 82944
#define U_B1F 84992
#define U_B2F 86016
#define U_TOTAL 86528

__global__ void prep_kernel(const float* __restrict__ W0, const float* __restrict__ b0,
                            const float* __restrict__ W1, const float* __restrict__ b1,
                            const float* __restrict__ W2, const float* __restrict__ b2,
                            const float* __restrict__ W3, f16* __restrict__ ws)
{
    int u = blockIdx.x * 256 + threadIdx.x;
    if (u >= U_TOTAL) return;
    int lane = u & 63;
    int l31 = lane & 31;
    int q = lane >> 5;
    f16x8 v;
#pragma unroll
    for (int e = 0; e < 8; ++e) v[e] = (f16)0.f;

    if (u < U_W2F) {                       // W1F: W1 is [1024][512]
        int jt = u >> 12, ks = (u >> 6) & 63;
        int j = jt * 32 + l31;
        int kb = ks * 16 + q * 8;
        const float* p = W1 + (size_t)kb * 512 + j;
#pragma unroll
        for (int e = 0; e < 8; ++e) v[e] = (f16)p[(size_t)e * 512];
    } else if (u < U_W3F) {                // W2F: W2 is [512][256]
        int t = u - U_W2F;
        int jt = t >> 11, ks = (t >> 6) & 31;
        int j = jt * 32 + l31;
        int kb = ks * 16 + q * 8;
        const float* p = W2 + (size_t)kb * 256 + j;
#pragma unroll
        for (int e = 0; e < 8; ++e) v[e] = (f16)p[(size_t)e * 256];
    } else if (u < U_P0F) {                // W3F: W3 is [256][3], pad j>=3 with 0
        int t = u - U_W3F;
        int ks = t >> 6;
        int j = l31;
        int kb = ks * 16 + q * 8;
        if (j < 3) {
            const float* p = W3 + (size_t)kb * 3 + j;
#pragma unroll
            for (int e = 0; e < 8; ++e) v[e] = (f16)p[(size_t)e * 3];
        }
    } else if (u < U_B1F) {                // P0F: layer-1 A frag with hi/lo split + bias
        int t = u - U_P0F;
        int jt = t >> 6;
        int j = jt * 32 + l31;
        if (q == 0) {
            float w00 = W0[j], w01 = W0[1024 + j], bb = b0[j];
            f16 w00h = (f16)w00, w01h = (f16)w01, bh = (f16)bb;
            v[0] = w00h; v[1] = w01h; v[2] = bh;
            v[3] = w00h; v[4] = w01h;                       // pair with x_lo
            v[5] = (f16)(w00 - (float)w00h);                // w_lo * x_hi
            v[6] = (f16)(w01 - (float)w01h);
            v[7] = (f16)(bb - (float)bh);                   // bias residual * 1
        }
    } else if (u < U_B2F) {                // B1F
        int t = u - U_B1F;
        int jt = t >> 6;
        int j = jt * 32 + l31;
        if (q == 0) v[0] = (f16)b1[j];
    } else {                               // B2F
        int t = u - U_B2F;
        int jt = t >> 6;
        int j = jt * 32 + l31;
        if (q == 0) v[0] = (f16)b2[j];
    }
    ((f16x8*)ws)[u] = v;
}

// ---- LDS slab, 16B-chunk XOR swizzle.
// Logical: row m (batch), 16B chunk c (8 f16 feats). Physical chunk =
// c ^ (m & 15). Bijective; spreads the bank-aligned row stride.
__device__ __forceinline__ void slab_wr8(unsigned char* lds_, int m, int c, int q8,
                                         int rs, f16x4 val)
{
    *(f16x4*)(lds_ + (size_t)m * rs + (size_t)(((c ^ (m & 15)) << 4) + q8)) = val;
}

__device__ __forceinline__ f16x8 slab_rd(const unsigned char* p, int rowbyte, int physc)
{
    return *(const f16x8*)(p + (size_t)rowbyte + (size_t)(physc << 4));
}

__device__ __forceinline__ f16x4 relu_pack4(const f32x16& d, int t)
{
    f16x4 pk;
#pragma unroll
    for (int r = 0; r < 4; ++r) {
        float v = d[4 * t + r];
        pk[r] = (f16)(v > 0.f ? v : 0.f);
    }
    return pk;
}

// rematerializable constants (R22): built at each use site.
__device__ __forceinline__ f32x16 zf()
{
    f32x16 z;
#pragma unroll
    for (int i = 0; i < 16; ++i) z[i] = 0.f;
    return z;
}

__device__ __forceinline__ f16x8 mk_ones(int q)
{
    f16x8 o;
#pragma unroll
    for (int e = 0; e < 8; ++e) o[e] = (f16)0.f;
    if (q == 0) o[0] = (f16)1.f;
    return o;
}

__global__ __launch_bounds__(512, 2)
void mlp_kernel(const float* __restrict__ X, const float* __restrict__ b3,
                const f16* __restrict__ ws, float* __restrict__ out)
{
    const f16x8* W1F = (const f16x8*)ws + U_W1F;
    const f16x8* W2F = (const f16x8*)ws + U_W2F;
    const f16x8* W3F = (const f16x8*)ws + U_W3F;
    const f16x8* P0F = (const f16x8*)ws + U_P0F;
    const f16x8* B1F = (const f16x8*)ws + U_B1F;
    const f16x8* B2F = (const f16x8*)ws + U_B2F;

    // 2 x 64KB dbuf chunk slabs (128 rows x 256 f16, rs=512B);
    // tail: whole 128KB = h2 slab (rs=1024B), then lower 64KB = h3 slab.
    __shared__ __align__(16) unsigned char lds[131072];

    const int tid  = threadIdx.x;
    const int w    = tid >> 6;       // wave 0..7
    const int lane = tid & 63;
    const int l31  = lane & 31;
    const int q    = lane >> 5;
    const int q8   = q << 3;
    const int pre  = q ^ (l31 & 15); // physc = (2ks) ^ pre
    const int ph   = w >> 2;         // ks-rotation phase: co-SIMD pair (w, w+4)
    const int preR = pre ^ (ph << 4);          // rotation folded into bf swizzle
    const int inc7  = ph ? -960 : 64;          // af walk: jump at loaded-pos 7->8
    const int inc15 = ph ? 1088 : 64;          // af walk: chunk boundary jump
    const size_t rowbase = (size_t)blockIdx.x * 128;

    // X frags, all 4 m-tiles (hi/lo split -> layer 1 ~exact); 16 regs
    f16x8 xfrag[4];
#pragma unroll
    for (int mt = 0; mt < 4; ++mt) {
        f16x8 v;
#pragma unroll
        for (int e = 0; e < 8; ++e) v[e] = (f16)0.f;
        if (q == 0) {
            float2 xv = ((const float2*)X)[rowbase + mt * 32 + l31];
            f16 x0h = (f16)xv.x, x1h = (f16)xv.y;
            v[0] = x0h; v[1] = x1h; v[2] = (f16)1.f;
            v[3] = (f16)(xv.x - (float)x0h);
            v[4] = (f16)(xv.y - (float)x1h);
            v[5] = x0h; v[6] = x1h; v[7] = (f16)1.f;
        }
        xfrag[mt] = v;
    }

    // Layer-2 ownership: wave w -> jt {2w, 2w+1} x all 4 mt. acc = 128 AGPR.
    f32x16 acc2[2][4];
#pragma unroll
    for (int ji = 0; ji < 2; ++ji) {
        f32x16 binit = MFMA(B1F[(2 * w + ji) * 64 + lane], mk_ones(q), zf());
#pragma unroll
        for (int mt = 0; mt < 4; ++mt) acc2[ji][mt] = binit;
    }

    // af streams: W1F jt-slices {2w, 2w+1}, 2-deep staging, rotated order.
    // af(s) = s*64 + (ph ? (s%16<8 ? +512 : -512) : 0); walk via inc7/inc15.
    const f16x8* __restrict__ ap0 = W1F + (size_t)(2 * w * 64) * 64 + lane + (ph << 9);
    const f16x8* __restrict__ ap1 = ap0 + 64 * 64;
    f16x8 a0c = ap0[0],  a1c = ap1[0];     // af[s=0]
    f16x8 a0n = ap0[64], a1n = ap1[64];    // af[s=1]
    ap0 += 128; ap1 += 128;                // next load = af[s=2]

    // prologue: layer1 chunk 0 -> buf0. Wave w: k1-tile w, all 4 m-tiles.
    {
        f16x8 af1 = P0F[w * 64 + lane];
#pragma unroll
        for (int mt = 0; mt < 4; ++mt) {
            f32x16 d = MFMA(af1, xfrag[mt], zf());
            int m = mt * 32 + l31;
#pragma unroll
            for (int t = 0; t < 4; ++t)
                slab_wr8(lds, m, w * 4 + t, q8, 512, relu_pack4(d, t));
        }
    }
    BARRIER();

    const int r0 = l31 * 512;              // bf row-byte bases, chunk slab
    const int r1 = r0 + 32 * 512;
    const int r2 = r0 + 64 * 512;
    const int r3 = r0 + 96 * 512;

    // ---- fused layer1+layer2: K chunked 4 x 256, dbuf slabs, 1 barrier/chunk.
    // Each wave consumes the chunk's 16 ks rotated by 8*ph (order-invariant).
    for (int c = 0; c < 4; ++c) {
        const unsigned char* rb = lds + (size_t)(c & 1) * 65536;
        // P0F for the NEXT chunk's regen: issue ~8K cy ahead of use.
        f16x8 p0nx;
        if (c < 3) p0nx = P0F[((c + 1) * 8 + w) * 64 + lane];
        // cold-start bf[kk=0] for this chunk (rotated slot = preR fold)
        f16x8 b0 = slab_rd(rb, r0, preR);
        f16x8 b1 = slab_rd(rb, r1, preR);
        f16x8 b2 = slab_rd(rb, r2, preR);
        f16x8 b3f = slab_rd(rb, r3, preR);
#pragma unroll
        for (int ks = 0; ks < 16; ++ks) {
            // issue af[s+2] (2-deep slack ~2 ks-rounds >> L2 latency)
            f16x8 a0f = ap0[0], a1f = ap1[0];
            int inc = (ks == 5) ? inc7 : (ks == 13) ? inc15 : 64;
            ap0 += inc; ap1 += inc;        // final overrun into W2F: in-bounds
            // issue bf[kk+1] WRAPPED (unconditional; ks=15 reads slot 0 again
            // -> in-bounds, value dead after loop). Rotation below is pure SSA.
            int pc = (2 * ((ks + 1) & 15)) ^ preR;
            f16x8 n0 = slab_rd(rb, r0, pc);
            f16x8 n1 = slab_rd(rb, r1, pc);
            f16x8 n2 = slab_rd(rb, r2, pc);
            f16x8 n3 = slab_rd(rb, r3, pc);
            // 8 MFMAs on staged operands (T5: prio boost the MFMA cluster)
            __builtin_amdgcn_s_setprio(1);
            acc2[0][0] = MFMA(a0c, b0,  acc2[0][0]);
            acc2[0][1] = MFMA(a0c, b1,  acc2[0][1]);
            acc2[1][0] = MFMA(a1c, b0,  acc2[1][0]);
            acc2[1][1] = MFMA(a1c, b1,  acc2[1][1]);
            acc2[0][2] = MFMA(a0c, b2,  acc2[0][2]);
            acc2[0][3] = MFMA(a0c, b3f, acc2[0][3]);
            acc2[1][2] = MFMA(a1c, b2,  acc2[1][2]);
            acc2[1][3] = MFMA(a1c, b3f, acc2[1][3]);
            __builtin_amdgcn_s_setprio(0);
            // rotate stages unconditionally (full unroll -> pure SSA renames)
            a0c = a0n; a1c = a1n; a0n = a0f; a1n = a1f;
            b0 = n0; b1 = n1; b2 = n2; b3f = n3;
        }
        // layer 1 for next chunk -> other buffer (P0F already in p0nx)
        if (c < 3) {
            unsigned char* wb = lds + (size_t)((c + 1) & 1) * 65536;
#pragma unroll
            for (int mt = 0; mt < 4; ++mt) {
                f32x16 d = MFMA(p0nx, xfrag[mt], zf());
                int m = mt * 32 + l31;
#pragma unroll
                for (int tt = 0; tt < 4; ++tt)
                    slab_wr8(wb, m, w * 4 + tt, q8, 512, relu_pack4(d, tt));
            }
        }
        BARRIER();
    }

    // ---- tail: stage h2 (128 rows x 512 f16, rs=1024B = 128KB).
#pragma unroll
    for (int ji = 0; ji < 2; ++ji) {
#pragma unroll
        for (int mt = 0; mt < 4; ++mt) {
            int m = mt * 32 + l31;
#pragma unroll
            for (int t = 0; t < 4; ++t)
                slab_wr8(lds, m, (2 * w + ji) * 4 + t, q8, 1024,
                         relu_pack4(acc2[ji][mt], t));
        }
    }
    BARRIER();

    // layer 3: wave (jp3 = w&3, mq = w>>2) -> jt {2jp3, 2jp3+1} x mt {2mq, 2mq+1};
    // K=512. Pipelined: af 2-deep, bf 1-ahead (wrapped). acc3 = 64 AGPR.
    const int jp3 = w & 3;
    const int mq  = w >> 2;
    f32x16 acc3[2][2];
#pragma unroll
    for (int ji = 0; ji < 2; ++ji) {
        f32x16 binit = MFMA(B2F[(2 * jp3 + ji) * 64 + lane], mk_ones(q), zf());
        acc3[ji][0] = binit;
        acc3[ji][1] = binit;
    }
    {
        const f16x8* __restrict__ bp0 = W2F + (size_t)(2 * jp3 * 32) * 64 + lane;
        const f16x8* __restrict__ bp1 = bp0 + 32 * 64;
        f16x8 c0c = bp0[0],  c1c = bp1[0];
        f16x8 c0n = bp0[64], c1n = bp1[64];
        bp0 += 128; bp1 += 128;
        const int s0 = (mq * 64 + l31) * 1024;   // h2 slab rows, rs=1024
        const int s1 = s0 + 32 * 1024;
        f16x8 d0 = slab_rd(lds, s0, pre);
        f16x8 d1 = slab_rd(lds, s1, pre);
#pragma unroll
        for (int ks = 0; ks < 32; ++ks) {
            f16x8 c0f = bp0[0], c1f = bp1[0];
            bp0 += 64; bp1 += 64;          // final overrun into W3F: in-bounds
            // wrapped bf prefetch (unconditional; ks=31 re-reads slot 0)
            int pc = (2 * ((ks + 1) & 31)) ^ pre;
            f16x8 e0 = slab_rd(lds, s0, pc);
            f16x8 e1 = slab_rd(lds, s1, pc);
            __builtin_amdgcn_s_setprio(1);
            acc3[0][0] = MFMA(c0c, d0, acc3[0][0]);
            acc3[0][1] = MFMA(c0c, d1, acc3[0][1]);
            acc3[1][0] = MFMA(c1c, d0, acc3[1][0]);
            acc3[1][1] = MFMA(c1c, d1, acc3[1][1]);
            __builtin_amdgcn_s_setprio(0);
            c0c = c0n; c1c = c1n; c0n = c0f; c1n = c1f;
            d0 = e0; d1 = e1;
        }
    }
    BARRIER();

    // stage h3 (128 rows x 256 f16, rs=512B = 64KB, lower half of slab)
    {
#pragma unroll
        for (int ji = 0; ji < 2; ++ji) {
#pragma unroll
            for (int mi = 0; mi < 2; ++mi) {
                int m = mq * 64 + mi * 32 + l31;
#pragma unroll
                for (int t = 0; t < 4; ++t)
                    slab_wr8(lds, m, (2 * jp3 + ji) * 4 + t, q8, 512,
                             relu_pack4(acc3[ji][mi], t));
            }
        }
    }
    BARRIER();

    // layer 4: waves 0..3 -> the four 32-row tiles (j padded, 3 valid).
    if (w < 4) {
        f32x16 acc4 = zf();
        const int s4 = (w * 32 + l31) * 512;
#pragma unroll
        for (int ks = 0; ks < 16; ++ks) {
            f16x8 af = W3F[ks * 64 + lane];
            f16x8 bf = slab_rd(lds, s4, (2 * ks) ^ pre);
            acc4 = MFMA(af, bf, acc4);
        }
        if (q == 0) {
            size_t gm = rowbase + w * 32 + l31;
            out[gm * 3 + 0] = acc4[0] + b3[0];
            out[gm * 3 + 1] = acc4[1] + b3[1];
            out[gm * 3 + 2] = acc4[2] + b3[2];
        }
    }
}

extern "C" void kernel_launch(void* const* d_in, const int* in_sizes, int n_in,
                              void* d_out, int out_size, void* d_ws, size_t ws_size,
                              hipStream_t stream)
{
    const float* X  = (const float*)d_in[0];
    const float* W0 = (const float*)d_in[1];
    const float* b0 = (const float*)d_in[2];
    const float* W1 = (const float*)d_in[3];
    const float* b1 = (const float*)d_in[4];
    const float* W2 = (const float*)d_in[5];
    const float* b2 = (const float*)d_in[6];
    const float* W3 = (const float*)d_in[7];
    const float* b3 = (const float*)d_in[8];
    f16* ws = (f16*)d_ws;

    int N = in_sizes[0] / 2;          // 262144
    int nblk = N / 128;               // 2048

    prep_kernel<<<(U_TOTAL + 255) / 256, 256, 0, stream>>>(W0, b0, W1, b1, W2, b2, W3, ws);
    mlp_kernel<<<nblk, 512, 0, stream>>>(X, b3, ws, (float*)d_out);
}

// Round 18
// 353.743 us; speedup vs baseline: 1.0308x; 1.0242x over previous
//
#include <hip/hip_runtime.h>

// Fused 4-layer MLP (2 -> 1024 -> 512 -> 256 -> 3), N = 262144, fp32 I/O.
// R25 = FINAL: exact R15 (307us, passed twice). R24 (=R21, lgkmcnt-only
// barriers) passed initial verify but DIVERGED after repeated graph replays
// (post-timing absmax 0.12) — a rare replay-dependent race. The relaxed
// barrier was the only semantic delta vs the twice-passing R15, and its
// measured benefit was null (307.8 vs 307.0) -> revert to full
// __syncthreads() (vmcnt+lgkmcnt drain; conservative, verified).
// Session summary: 374 -> 307us (-18%). Three structurally distinct
// kernels (1blk/CU lockstep+skew, 2blk/CU co-res x2) converge at ~307us =
// 1.87x the ~164us MFMA-issue floor at MfmaUtil 55%. Constraint net:
// operand-intensity walls (L2 af-stream, LDS bf-stream) force acc2=128
// AGPR -> <=2 waves/SIMD; the ks-loop body sits exactly at the 128-VGPR
// edge (any in-loop addition spills — proven R10/R16/R19/R20). Remaining
// gap is 2-wave/SIMD scheduling latency, not a saturated pipe.
// Structure: 512 thr (8 waves), 128 rows/block, fp16 MFMA 32x32x16, fp32
// accumulate, transposed layers D[feat][batch]; K chunked 4x256 through
// 2x64KB dbuf LDS slabs (16B-chunk XOR swizzle); af 2-deep reg-staged,
// bf 1-ahead; co-SIMD ks-rotation skew + setprio (+8%, R15); P0F
// prefetched a chunk ahead; layer-1 A-frags precomputed with hi/lo split;
// weights pre-swizzled into MFMA fragment layout by prep_kernel.

typedef _Float16 f16;
typedef f16 f16x8 __attribute__((ext_vector_type(8)));
typedef f16 f16x4 __attribute__((ext_vector_type(4)));
typedef float f32x16 __attribute__((ext_vector_type(16)));

#define MFMA(a, b, c) __builtin_amdgcn_mfma_f32_32x32x16_f16((a), (b), (c), 0, 0, 0)

// ws layout in 16-byte units (f16x8):
//  W1F : [16 jt][64 ks][64 lane]            ->      0 .. 65536
//  W2F : [ 8 jt][32 ks][64 lane]            ->  65536 .. 81920
//  W3F : [16 ks][64 lane]                   ->  81920 .. 82944
//  P0F : [32 k1t][64 lane] (layer1 A frag)  ->  82944 .. 84992
//  B1F : [16 jt][64 lane]                   ->  84992 .. 86016
//  B2F : [ 8 jt][64 lane]                   ->  86016 .. 86528
#define U_W1F 0
#define U_W2F 65536
#define U_W3F 81920
#define U_P0F 82944
#define U_B1F 84992
#define U_B2F 86016
#define U_TOTAL 86528

__global__ void prep_kernel(const float* __restrict__ W0, const float* __restrict__ b0,
                            const float* __restrict__ W1, const float* __restrict__ b1,
                            const float* __restrict__ W2, const float* __restrict__ b2,
                            const float* __restrict__ W3, f16* __restrict__ ws)
{
    int u = blockIdx.x * 256 + threadIdx.x;
    if (u >= U_TOTAL) return;
    int lane = u & 63;
    int l31 = lane & 31;
    int q = lane >> 5;
    f16x8 v;
#pragma unroll
    for (int e = 0; e < 8; ++e) v[e] = (f16)0.f;

    if (u < U_W2F) {                       // W1F: W1 is [1024][512]
        int jt = u >> 12, ks = (u >> 6) & 63;
        int j = jt * 32 + l31;
        int kb = ks * 16 + q * 8;
        const float* p = W1 + (size_t)kb * 512 + j;
#pragma unroll
        for (int e = 0; e < 8; ++e) v[e] = (f16)p[(size_t)e * 512];
    } else if (u < U_W3F) {                // W2F: W2 is [512][256]
        int t = u - U_W2F;
        int jt = t >> 11, ks = (t >> 6) & 31;
        int j = jt * 32 + l31;
        int kb = ks * 16 + q * 8;
        const float* p = W2 + (size_t)kb * 256 + j;
#pragma unroll
        for (int e = 0; e < 8; ++e) v[e] = (f16)p[(size_t)e * 256];
    } else if (u < U_P0F) {                // W3F: W3 is [256][3], pad j>=3 with 0
        int t = u - U_W3F;
        int ks = t >> 6;
        int j = l31;
        int kb = ks * 16 + q * 8;
        if (j < 3) {
            const float* p = W3 + (size_t)kb * 3 + j;
#pragma unroll
            for (int e = 0; e < 8; ++e) v[e] = (f16)p[(size_t)e * 3];
        }
    } else if (u < U_B1F) {                // P0F: layer-1 A frag with hi/lo split + bias
        int t = u - U_P0F;
        int jt = t >> 6;
        int j = jt * 32 + l31;
        if (q == 0) {
            float w00 = W0[j], w01 = W0[1024 + j], bb = b0[j];
            f16 w00h = (f16)w00, w01h = (f16)w01, bh = (f16)bb;
            v[0] = w00h; v[1] = w01h; v[2] = bh;
            v[3] = w00h; v[4] = w01h;                       // pair with x_lo
            v[5] = (f16)(w00 - (float)w00h);                // w_lo * x_hi
            v[6] = (f16)(w01 - (float)w01h);
            v[7] = (f16)(bb - (float)bh);                   // bias residual * 1
        }
    } else if (u < U_B2F) {                // B1F
        int t = u - U_B1F;
        int jt = t >> 6;
        int j = jt * 32 + l31;
        if (q == 0) v[0] = (f16)b1[j];
    } else {                               // B2F
        int t = u - U_B2F;
        int jt = t >> 6;
        int j = jt * 32 + l31;
        if (q == 0) v[0] = (f16)b2[j];
    }
    ((f16x8*)ws)[u] = v;
}

// ---- LDS slab, 16B-chunk XOR swizzle.
// Logical: row m (batch), 16B chunk c (8 f16 feats). Physical chunk =
// c ^ (m & 15). Bijective; spreads the bank-aligned row stride.
__device__ __forceinline__ void slab_wr8(unsigned char* lds_, int m, int c, int q8,
                                         int rs, f16x4 val)
{
    *(f16x4*)(lds_ + (size_t)m * rs + (size_t)(((c ^ (m & 15)) << 4) + q8)) = val;
}

__device__ __forceinline__ f16x8 slab_rd(const unsigned char* p, int rowbyte, int physc)
{
    return *(const f16x8*)(p + (size_t)rowbyte + (size_t)(physc << 4));
}

__device__ __forceinline__ f16x4 relu_pack4(const f32x16& d, int t)
{
    f16x4 pk;
#pragma unroll
    for (int r = 0; r < 4; ++r) {
        float v = d[4 * t + r];
        pk[r] = (f16)(v > 0.f ? v : 0.f);
    }
    return pk;
}

__global__ __launch_bounds__(512, 2)
void mlp_kernel(const float* __restrict__ X, const float* __restrict__ b3,
                const f16* __restrict__ ws, float* __restrict__ out)
{
    const f16x8* W1F = (const f16x8*)ws + U_W1F;
    const f16x8* W2F = (const f16x8*)ws + U_W2F;
    const f16x8* W3F = (const f16x8*)ws + U_W3F;
    const f16x8* P0F = (const f16x8*)ws + U_P0F;
    const f16x8* B1F = (const f16x8*)ws + U_B1F;
    const f16x8* B2F = (const f16x8*)ws + U_B2F;

    // 2 x 64KB dbuf chunk slabs (128 rows x 256 f16, rs=512B);
    // tail: whole 128KB = h2 slab (rs=1024B), then lower 64KB = h3 slab.
    __shared__ __align__(16) unsigned char lds[131072];

    const int tid  = threadIdx.x;
    const int w    = tid >> 6;       // wave 0..7
    const int lane = tid & 63;
    const int l31  = lane & 31;
    const int q    = lane >> 5;
    const int q8   = q << 3;
    const int pre  = q ^ (l31 & 15); // physc = (2ks) ^ pre
    const int ph   = w >> 2;         // ks-rotation phase: co-SIMD pair (w, w+4)
    const int preR = pre ^ (ph << 4);          // rotation folded into bf swizzle
    const int inc7  = ph ? -960 : 64;          // af walk: jump at loaded-pos 7->8
    const int inc15 = ph ? 1088 : 64;          // af walk: chunk boundary jump
    const size_t rowbase = (size_t)blockIdx.x * 128;

    f32x16 zero16;
#pragma unroll
    for (int i = 0; i < 16; ++i) zero16[i] = 0.f;

    // ones frag for bias-init MFMAs
    f16x8 ones;
#pragma unroll
    for (int e = 0; e < 8; ++e) ones[e] = (f16)0.f;
    if (q == 0) ones[0] = (f16)1.f;

    // X frags, all 4 m-tiles (hi/lo split -> layer 1 ~exact); 16 regs
    f16x8 xfrag[4];
#pragma unroll
    for (int mt = 0; mt < 4; ++mt) {
        f16x8 v;
#pragma unroll
        for (int e = 0; e < 8; ++e) v[e] = (f16)0.f;
        if (q == 0) {
            float2 xv = ((const float2*)X)[rowbase + mt * 32 + l31];
            f16 x0h = (f16)xv.x, x1h = (f16)xv.y;
            v[0] = x0h; v[1] = x1h; v[2] = (f16)1.f;
            v[3] = (f16)(xv.x - (float)x0h);
            v[4] = (f16)(xv.y - (float)x1h);
            v[5] = x0h; v[6] = x1h; v[7] = (f16)1.f;
        }
        xfrag[mt] = v;
    }

    // Layer-2 ownership: wave w -> jt {2w, 2w+1} x all 4 mt. acc = 128 AGPR.
    f32x16 acc2[2][4];
#pragma unroll
    for (int ji = 0; ji < 2; ++ji) {
        f32x16 binit = MFMA(B1F[(2 * w + ji) * 64 + lane], ones, zero16);
#pragma unroll
        for (int mt = 0; mt < 4; ++mt) acc2[ji][mt] = binit;
    }

    // af streams: W1F jt-slices {2w, 2w+1}, 2-deep staging, rotated order.
    // af(s) = s*64 + (ph ? (s%16<8 ? +512 : -512) : 0); walk via inc7/inc15.
    const f16x8* __restrict__ ap0 = W1F + (size_t)(2 * w * 64) * 64 + lane + (ph << 9);
    const f16x8* __restrict__ ap1 = ap0 + 64 * 64;
    f16x8 a0c = ap0[0],  a1c = ap1[0];     // af[s=0]
    f16x8 a0n = ap0[64], a1n = ap1[64];    // af[s=1]
    ap0 += 128; ap1 += 128;                // next load = af[s=2]

    // prologue: layer1 chunk 0 -> buf0. Wave w: k1-tile w, all 4 m-tiles.
    {
        f16x8 af1 = P0F[w * 64 + lane];
#pragma unroll
        for (int mt = 0; mt < 4; ++mt) {
            f32x16 d = MFMA(af1, xfrag[mt], zero16);
            int m = mt * 32 + l31;
#pragma unroll
            for (int t = 0; t < 4; ++t)
                slab_wr8(lds, m, w * 4 + t, q8, 512, relu_pack4(d, t));
        }
    }
    __syncthreads();

    const int r0 = l31 * 512;              // bf row-byte bases, chunk slab
    const int r1 = r0 + 32 * 512;
    const int r2 = r0 + 64 * 512;
    const int r3 = r0 + 96 * 512;

    // ---- fused layer1+layer2: K chunked 4 x 256, dbuf slabs, 1 barrier/chunk.
    // Each wave consumes the chunk's 16 ks rotated by 8*ph (order-invariant).
    for (int c = 0; c < 4; ++c) {
        const unsigned char* rb = lds + (size_t)(c & 1) * 65536;
        // P0F for the NEXT chunk's regen: issue ~8K cy ahead of use.
        f16x8 p0nx;
        if (c < 3) p0nx = P0F[((c + 1) * 8 + w) * 64 + lane];
        // cold-start bf[kk=0] for this chunk (rotated slot = preR fold)
        f16x8 b0 = slab_rd(rb, r0, preR);
        f16x8 b1 = slab_rd(rb, r1, preR);
        f16x8 b2 = slab_rd(rb, r2, preR);
        f16x8 b3f = slab_rd(rb, r3, preR);
#pragma unroll
        for (int ks = 0; ks < 16; ++ks) {
            // issue af[s+2] (2-deep slack ~2 ks-rounds >> L2 latency)
            f16x8 a0f = ap0[0], a1f = ap1[0];
            int inc = (ks == 5) ? inc7 : (ks == 13) ? inc15 : 64;
            ap0 += inc; ap1 += inc;        // final overrun into W2F: in-bounds
            // issue bf[kk+1] (1-ahead slack ~1 ks-round >> LDS latency)
            f16x8 n0, n1, n2, n3;
            if (ks < 15) {
                int pc = (2 * (ks + 1)) ^ preR;
                n0 = slab_rd(rb, r0, pc);
                n1 = slab_rd(rb, r1, pc);
                n2 = slab_rd(rb, r2, pc);
                n3 = slab_rd(rb, r3, pc);
            }
            // 8 MFMAs on staged operands (T5: prio boost the MFMA cluster)
            __builtin_amdgcn_s_setprio(1);
            acc2[0][0] = MFMA(a0c, b0,  acc2[0][0]);
            acc2[0][1] = MFMA(a0c, b1,  acc2[0][1]);
            acc2[1][0] = MFMA(a1c, b0,  acc2[1][0]);
            acc2[1][1] = MFMA(a1c, b1,  acc2[1][1]);
            acc2[0][2] = MFMA(a0c, b2,  acc2[0][2]);
            acc2[0][3] = MFMA(a0c, b3f, acc2[0][3]);
            acc2[1][2] = MFMA(a1c, b2,  acc2[1][2]);
            acc2[1][3] = MFMA(a1c, b3f, acc2[1][3]);
            __builtin_amdgcn_s_setprio(0);
            // rotate stages (full unroll -> pure SSA renames)
            a0c = a0n; a1c = a1n; a0n = a0f; a1n = a1f;
            if (ks < 15) { b0 = n0; b1 = n1; b2 = n2; b3f = n3; }
        }
        // layer 1 for next chunk -> other buffer (P0F already in p0nx)
        if (c < 3) {
            unsigned char* wb = lds + (size_t)((c + 1) & 1) * 65536;
#pragma unroll
            for (int mt = 0; mt < 4; ++mt) {
                f32x16 d = MFMA(p0nx, xfrag[mt], zero16);
                int m = mt * 32 + l31;
#pragma unroll
                for (int tt = 0; tt < 4; ++tt)
                    slab_wr8(wb, m, w * 4 + tt, q8, 512, relu_pack4(d, tt));
            }
        }
        __syncthreads();
    }

    // ---- tail: stage h2 (128 rows x 512 f16, rs=1024B = 128KB).
#pragma unroll
    for (int ji = 0; ji < 2; ++ji) {
#pragma unroll
        for (int mt = 0; mt < 4; ++mt) {
            int m = mt * 32 + l31;
#pragma unroll
            for (int t = 0; t < 4; ++t)
                slab_wr8(lds, m, (2 * w + ji) * 4 + t, q8, 1024,
                         relu_pack4(acc2[ji][mt], t));
        }
    }
    __syncthreads();

    // layer 3: wave (jp3 = w&3, mq = w>>2) -> jt {2jp3, 2jp3+1} x mt {2mq, 2mq+1};
    // K=512. Pipelined: af 2-deep, bf 1-ahead. acc3 = 64 AGPR.
    // Co-SIMD diversity here comes from mq differing for (w, w+4).
    const int jp3 = w & 3;
    const int mq  = w >> 2;
    f32x16 acc3[2][2];
#pragma unroll
    for (int ji = 0; ji < 2; ++ji) {
        f32x16 binit = MFMA(B2F[(2 * jp3 + ji) * 64 + lane], ones, zero16);
        acc3[ji][0] = binit;
        acc3[ji][1] = binit;
    }
    {
        const f16x8* __restrict__ bp0 = W2F + (size_t)(2 * jp3 * 32) * 64 + lane;
        const f16x8* __restrict__ bp1 = bp0 + 32 * 64;
        f16x8 c0c = bp0[0],  c1c = bp1[0];
        f16x8 c0n = bp0[64], c1n = bp1[64];
        bp0 += 128; bp1 += 128;
        const int s0 = (mq * 64 + l31) * 1024;   // h2 slab rows, rs=1024
        const int s1 = s0 + 32 * 1024;
        f16x8 d0 = slab_rd(lds, s0, pre);
        f16x8 d1 = slab_rd(lds, s1, pre);
#pragma unroll
        for (int ks = 0; ks < 32; ++ks) {
            f16x8 c0f = bp0[0], c1f = bp1[0];
            bp0 += 64; bp1 += 64;          // final overrun into W3F: in-bounds
            f16x8 e0, e1;
            if (ks < 31) {
                int pc = (2 * (ks + 1)) ^ pre;
                e0 = slab_rd(lds, s0, pc);
                e1 = slab_rd(lds, s1, pc);
            }
            __builtin_amdgcn_s_setprio(1);
            acc3[0][0] = MFMA(c0c, d0, acc3[0][0]);
            acc3[0][1] = MFMA(c0c, d1, acc3[0][1]);
            acc3[1][0] = MFMA(c1c, d0, acc3[1][0]);
            acc3[1][1] = MFMA(c1c, d1, acc3[1][1]);
            __builtin_amdgcn_s_setprio(0);
            c0c = c0n; c1c = c1n; c0n = c0f; c1n = c1f;
            if (ks < 31) { d0 = e0; d1 = e1; }
        }
    }
    __syncthreads();

    // stage h3 (128 rows x 256 f16, rs=512B = 64KB, lower half of slab)
    {
#pragma unroll
        for (int ji = 0; ji < 2; ++ji) {
#pragma unroll
            for (int mi = 0; mi < 2; ++mi) {
                int m = mq * 64 + mi * 32 + l31;
#pragma unroll
                for (int t = 0; t < 4; ++t)
                    slab_wr8(lds, m, (2 * jp3 + ji) * 4 + t, q8, 512,
                             relu_pack4(acc3[ji][mi], t));
            }
        }
    }
    __syncthreads();

    // layer 4: waves 0..3 -> the four 32-row tiles (j padded, 3 valid).
    if (w < 4) {
        f32x16 acc4 = zero16;
        const int s4 = (w * 32 + l31) * 512;
#pragma unroll
        for (int ks = 0; ks < 16; ++ks) {
            f16x8 af = W3F[ks * 64 + lane];
            f16x8 bf = slab_rd(lds, s4, (2 * ks) ^ pre);
            acc4 = MFMA(af, bf, acc4);
        }
        if (q == 0) {
            size_t gm = rowbase + w * 32 + l31;
            out[gm * 3 + 0] = acc4[0] + b3[0];
            out[gm * 3 + 1] = acc4[1] + b3[1];
            out[gm * 3 + 2] = acc4[2] + b3[2];
        }
    }
}

extern "C" void kernel_launch(void* const* d_in, const int* in_sizes, int n_in,
                              void* d_out, int out_size, void* d_ws, size_t ws_size,
                              hipStream_t stream)
{
    const float* X  = (const float*)d_in[0];
    const float* W0 = (const float*)d_in[1];
    const float* b0 = (const float*)d_in[2];
    const float* W1 = (const float*)d_in[3];
    const float* b1 = (const float*)d_in[4];
    const float* W2 = (const float*)d_in[5];
    const float* b2 = (const float*)d_in[6];
    const float* W3 = (const float*)d_in[7];
    const float* b3 = (const float*)d_in[8];
    f16* ws = (f16*)d_ws;

    int N = in_sizes[0] / 2;          // 262144
    int nblk = N / 128;               // 2048

    prep_kernel<<<(U_TOTAL + 255) / 256, 256, 0, stream>>>(W0, b0, W1, b1, W2, b2, W3, ws);
    mlp_kernel<<<nblk, 512, 0, stream>>>(X, b3, ws, (float*)d_out);
}